// Round 7
// baseline (672.518 us; speedup 1.0000x reference)
//
#include <hip/hip_runtime.h>
#include <stdint.h>

typedef unsigned int u32;
typedef unsigned short u16;

#define NROWS 100000
#define DIM 512
#define HDIM 1024
#define OUTF 250
#define NSEG 256
#define LNEPS 1e-5f
#define BM 64
#define NT 1563            // ceil(100000/64); 1563*64 = 100032 padded rows
#define GATE_GRID 256

typedef __bf16 bf16_t;
typedef bf16_t bf16x4 __attribute__((ext_vector_type(4)));
typedef bf16_t bf16x8 __attribute__((ext_vector_type(8)));
typedef float f32x4 __attribute__((ext_vector_type(4)));

// raw barrier: drain LDS only, leave global_load_lds (vmcnt) in flight
#define BAR_LGKM() asm volatile("s_waitcnt lgkmcnt(0)\n\ts_barrier" ::: "memory")

__device__ inline int lower_bound(const int* __restrict__ a, int n, int v) {
    int lo = 0, hi = n;
    while (lo < hi) {
        int m = (lo + hi) >> 1;
        if (a[m] < v) lo = m + 1; else hi = m;
    }
    return lo;
}

// ---------------------------------------------------------------------------
// Kernel 0: weight conversion (gW1/mW1/mW2 -> bf16 MFMA-fragment order) and
// x fp32 -> x_bf16 PRE-SWIZZLED: global unit gid = i*64 + u_phys holds logical
// unit u = u_phys ^ (i&7) of row i (so global_load_lds linear writes land the
// swizzled LDS layout). Rows 100000..100031 zero-padded.
// ---------------------------------------------------------------------------
__global__ __launch_bounds__(256) void k_conv(const float* __restrict__ gW1,
                                              const float* __restrict__ mW1,
                                              const float* __restrict__ mW2,
                                              const float* __restrict__ x,
                                              u16* __restrict__ Wf,
                                              u16* __restrict__ mW1f,
                                              u16* __restrict__ mW2f,
                                              u16* __restrict__ xbf) {
    int bid = blockIdx.x;
    if (bid < 512) {
        const float* src_base = (bid < 256) ? gW1 : mW1;
        u16* dst = (bid < 256) ? Wf : mW1f;
        int gid  = (bid & 255) * 256 + threadIdx.x;   // 0..65535
        int lane = gid & 63;
        int grp  = gid >> 6;                          // ks*64 + nt
        int ks   = grp >> 6, nt = grp & 63;
        int n    = nt * 16 + (lane & 15);
        int k0   = ks * 32 + ((lane >> 4) << 3);
        const float* src = src_base + (size_t)n * DIM + k0;
        float4 f0 = *reinterpret_cast<const float4*>(src);
        float4 f1 = *reinterpret_cast<const float4*>(src + 4);
        bf16x8 v;
        v[0] = (bf16_t)f0.x; v[1] = (bf16_t)f0.y;
        v[2] = (bf16_t)f0.z; v[3] = (bf16_t)f0.w;
        v[4] = (bf16_t)f1.x; v[5] = (bf16_t)f1.y;
        v[6] = (bf16_t)f1.z; v[7] = (bf16_t)f1.w;
        reinterpret_cast<bf16x8*>(dst)[gid] = v;
    } else if (bid < 640) {
        int gid  = (bid - 512) * 256 + threadIdx.x;   // 0..32767
        int lane = gid & 63;
        int grp  = gid >> 6;                          // ks*16 + nt
        int ks   = grp >> 4, nt = grp & 15;
        int n    = nt * 16 + (lane & 15);             // 0..255
        int k0   = ks * 32 + ((lane >> 4) << 3);
        bf16x8 v;
        if (n < OUTF) {
            const float* src = mW2 + (size_t)n * HDIM + k0;
            float4 f0 = *reinterpret_cast<const float4*>(src);
            float4 f1 = *reinterpret_cast<const float4*>(src + 4);
            v[0] = (bf16_t)f0.x; v[1] = (bf16_t)f0.y;
            v[2] = (bf16_t)f0.z; v[3] = (bf16_t)f0.w;
            v[4] = (bf16_t)f1.x; v[5] = (bf16_t)f1.y;
            v[6] = (bf16_t)f1.z; v[7] = (bf16_t)f1.w;
        } else {
            #pragma unroll
            for (int j = 0; j < 8; ++j) v[j] = (bf16_t)0.f;
        }
        reinterpret_cast<bf16x8*>(mW2f)[gid] = v;
    } else {
        int gid = (bid - 640) * 256 + threadIdx.x;    // 0..6402047 (100032*64)
        int i   = gid >> 6;
        int up  = gid & 63;
        bf16x8 v;
        if (i < NROWS) {
            int u = up ^ (i & 7);
            const float* src = x + (size_t)i * DIM + (u << 3);
            float4 f0 = *reinterpret_cast<const float4*>(src);
            float4 f1 = *reinterpret_cast<const float4*>(src + 4);
            v[0] = (bf16_t)f0.x; v[1] = (bf16_t)f0.y;
            v[2] = (bf16_t)f0.z; v[3] = (bf16_t)f0.w;
            v[4] = (bf16_t)f1.x; v[5] = (bf16_t)f1.y;
            v[6] = (bf16_t)f1.z; v[7] = (bf16_t)f1.w;
        } else {
            #pragma unroll
            for (int j = 0; j < 8; ++j) v[j] = (bf16_t)0.f;
        }
        reinterpret_cast<bf16x8*>(xbf)[gid] = v;
    }
}

// ---------------------------------------------------------------------------
// Kernel 1: fused  gate[i] = relu(LN(x_i @ gW1.T + gb1)) . gW2 + gb2
// Persistent: 256 blocks (1/CU) x 1024 thr (16 waves). BM=64 tiles, LDS
// double-buffered 2x64KB, staged via global_load_lds (16B) from pre-swizzled
// x_bf16. Wave w owns cols [64w,64w+64): acc[4][4] = 64 AGPR. Next-tile stage
// issued after K-loop + const loads (vmcnt oldest-first keeps it in flight
// through the raw-lgkm-barrier epilogue); drained at loop-top __syncthreads.
// ---------------------------------------------------------------------------
__global__ __launch_bounds__(1024, 4) void k_gate(
    const u16* __restrict__ xbf, const u16* __restrict__ Wf,
    const float* __restrict__ gb1,
    const float* __restrict__ gln_g, const float* __restrict__ gln_b,
    const float* __restrict__ gW2, const float* __restrict__ gb2,
    float* __restrict__ gate)
{
    __shared__ __align__(16) u16 xlds[2][BM * DIM];   // 2 x 64KB
    __shared__ float redS[16][BM];
    __shared__ float redQ[16][BM];
    __shared__ float meanA[BM], rstdA[BM];

    const int tid  = threadIdx.x;
    const int lane = tid & 63;
    const int w    = tid >> 6;          // wave 0..15
    const int l15  = lane & 15;
    const int g4   = lane >> 4;         // 0..3

    const bf16x8* __restrict__ WfB = reinterpret_cast<const bf16x8*>(Wf);
    const float gb2v = gb2[0];          // scalar, hoisted (SGPR)

    auto stage = [&](int t, int buf) {
        #pragma unroll
        for (int uu = 0; uu < 4; ++uu) {
            const u16* gp = xbf + ((size_t)t * 4096 + uu * 1024 + tid) * 8;
            u16* lp = &xlds[buf][(uu * 1024 + w * 64) * 8];   // wave-uniform base
            __builtin_amdgcn_global_load_lds(
                (const __attribute__((address_space(1))) u32*)gp,
                (__attribute__((address_space(3))) u32*)lp, 16, 0, 0);
        }
    };

    stage(blockIdx.x, 0);
    int cur = 0;
    for (int t = blockIdx.x; t < NT; t += GATE_GRID) {
        __syncthreads();                 // drains vmcnt: buf[cur] ready
        const u16* xl = xlds[cur];

        f32x4 acc[4][4];
        #pragma unroll
        for (int m = 0; m < 4; ++m)
            #pragma unroll
            for (int t4 = 0; t4 < 4; ++t4)
                acc[m][t4] = (f32x4){0.f, 0.f, 0.f, 0.f};

        auto loadB = [&](bf16x8 (&b)[4], int ks) {
            #pragma unroll
            for (int t4 = 0; t4 < 4; ++t4)
                b[t4] = WfB[(ks * 64 + w * 4 + t4) * 64 + lane];
        };
        auto step = [&](bf16x8 (&b)[4], int ks) {
            bf16x8 a[4];
            #pragma unroll
            for (int m = 0; m < 4; ++m) {
                int r = m * 16 + l15;
                int u = ks * 4 + g4;
                a[m] = *reinterpret_cast<const bf16x8*>(&xl[r * DIM + ((u ^ (r & 7)) << 3)]);
            }
            #pragma unroll
            for (int m = 0; m < 4; ++m)
                #pragma unroll
                for (int t4 = 0; t4 < 4; ++t4)
                    acc[m][t4] = __builtin_amdgcn_mfma_f32_16x16x32_bf16(a[m], b[t4], acc[m][t4], 0, 0, 0);
        };

        bf16x8 b0[4], b1[4];
        loadB(b0, 0);
        #pragma unroll
        for (int ks2 = 0; ks2 < 8; ++ks2) {
            loadB(b1, 2 * ks2 + 1);
            step(b0, 2 * ks2);
            if (ks2 < 7) loadB(b0, 2 * ks2 + 2);
            step(b1, 2 * ks2 + 1);
        }

        // epilogue consts BEFORE staging issue (vmcnt oldest-first: using them
        // retires only these, staging stays outstanding)
        float cbias[4], cg[4], cb[4], cw[4];
        #pragma unroll
        for (int t4 = 0; t4 < 4; ++t4) {
            int c = (w * 4 + t4) * 16 + l15;
            cbias[t4] = gb1[c]; cg[t4] = gln_g[c]; cb[t4] = gln_b[c]; cw[t4] = gW2[c];
        }
        __builtin_amdgcn_sched_barrier(0);
        if (t + GATE_GRID < NT) stage(t + GATE_GRID, cur ^ 1);

        // bias add
        #pragma unroll
        for (int m = 0; m < 4; ++m)
            #pragma unroll
            for (int t4 = 0; t4 < 4; ++t4)
                #pragma unroll
                for (int j = 0; j < 4; ++j)
                    acc[m][t4][j] += cbias[t4];

        // per-row LN stats
        #pragma unroll
        for (int m = 0; m < 4; ++m) {
            #pragma unroll
            for (int j = 0; j < 4; ++j) {
                float s1 = 0.f, s2 = 0.f;
                #pragma unroll
                for (int t4 = 0; t4 < 4; ++t4) {
                    float v = acc[m][t4][j];
                    s1 += v; s2 += v * v;
                }
                #pragma unroll
                for (int off = 1; off < 16; off <<= 1) {
                    s1 += __shfl_xor(s1, off);
                    s2 += __shfl_xor(s2, off);
                }
                if (l15 == 0) {
                    int row = m * 16 + g4 * 4 + j;
                    redS[w][row] = s1;
                    redQ[w][row] = s2;
                }
            }
        }
        BAR_LGKM();
        if (tid < BM) {
            float S1 = 0.f, S2 = 0.f;
            #pragma unroll
            for (int ww = 0; ww < 16; ++ww) { S1 += redS[ww][tid]; S2 += redQ[ww][tid]; }
            float mean = S1 * (1.0f / 1024.0f);
            float var  = S2 * (1.0f / 1024.0f) - mean * mean;
            meanA[tid] = mean;
            rstdA[tid] = rsqrtf(var + LNEPS);
        }
        BAR_LGKM();

        // LN + relu + dot(gW2)
        #pragma unroll
        for (int m = 0; m < 4; ++m) {
            #pragma unroll
            for (int j = 0; j < 4; ++j) {
                int row = m * 16 + g4 * 4 + j;
                float mn = meanA[row];
                float rs = rstdA[row];
                float gp = 0.f;
                #pragma unroll
                for (int t4 = 0; t4 < 4; ++t4) {
                    float h = (acc[m][t4][j] - mn) * rs * cg[t4] + cb[t4];
                    gp += fmaxf(h, 0.f) * cw[t4];
                }
                #pragma unroll
                for (int off = 1; off < 16; off <<= 1)
                    gp += __shfl_xor(gp, off);
                if (l15 == 0) redS[w][row] = gp;
            }
        }
        BAR_LGKM();
        if (tid < BM) {
            float s = gb2v;
            #pragma unroll
            for (int ww = 0; ww < 16; ++ww) s += redS[ww][tid];
            int row = t * 64 + tid;
            if (row < NROWS) gate[row] = s;
        }
        cur ^= 1;
    }
}

// ---------------------------------------------------------------------------
// Kernel 2: per-segment max and sum(exp)
// ---------------------------------------------------------------------------
__global__ __launch_bounds__(256) void k_seg(const int* __restrict__ ids,
                                             const float* __restrict__ gate,
                                             float* __restrict__ segmax,
                                             float* __restrict__ segden) {
    int b = blockIdx.x, tid = threadIdx.x;
    int start = lower_bound(ids, NROWS, b);
    int end   = lower_bound(ids, NROWS, b + 1);
    __shared__ float sh[4];

    float lm = -INFINITY;
    for (int i = start + tid; i < end; i += 256) lm = fmaxf(lm, gate[i]);
    #pragma unroll
    for (int off = 32; off; off >>= 1) lm = fmaxf(lm, __shfl_xor(lm, off));
    if ((tid & 63) == 0) sh[tid >> 6] = lm;
    __syncthreads();
    float m = fmaxf(fmaxf(sh[0], sh[1]), fmaxf(sh[2], sh[3]));
    __syncthreads();

    float ls = 0.f;
    for (int i = start + tid; i < end; i += 256) ls += __expf(gate[i] - m);
    #pragma unroll
    for (int off = 32; off; off >>= 1) ls += __shfl_xor(ls, off);
    if ((tid & 63) == 0) sh[tid >> 6] = ls;
    __syncthreads();
    if (tid == 0) {
        segmax[b] = m;
        segden[b] = sh[0] + sh[1] + sh[2] + sh[3];
    }
}

// ---------------------------------------------------------------------------
// Kernel 3: partial pooled sums from x_bf16 (un-swizzling reads).
// grid (NSEG, 4); 512 thr = 8 row-stripes x 64 logical units.
// ---------------------------------------------------------------------------
__global__ __launch_bounds__(512) void k_poolp(const int* __restrict__ ids,
                                               const float* __restrict__ gate,
                                               const u16* __restrict__ xbf,
                                               const float* __restrict__ segmax,
                                               const float* __restrict__ segden,
                                               float* __restrict__ pooledp) {
    const int b = blockIdx.x, q = blockIdx.y, tid = threadIdx.x;
    const int s      = tid & 63;     // logical unit (8 cols)
    const int stripe = tid >> 6;     // 0..7
    const int start = lower_bound(ids, NROWS, b);
    const int end   = lower_bound(ids, NROWS, b + 1);
    const float m   = segmax[b];
    const float den = segden[b];
    const float inv = (den > 0.f) ? 1.0f / den : 0.0f;

    float acc[8];
    #pragma unroll
    for (int j = 0; j < 8; ++j) acc[j] = 0.f;

    for (int i = start + q * 8 + stripe; i < end; i += 32) {
        float wgt = __expf(gate[i] - m) * inv;
        bf16x8 xv = *reinterpret_cast<const bf16x8*>(xbf + ((size_t)i * 64 + (s ^ (i & 7))) * 8);
        #pragma unroll
        for (int j = 0; j < 8; ++j) acc[j] += wgt * (float)xv[j];
    }

    __shared__ float sh[8][64][8];   // 16KB
    #pragma unroll
    for (int j = 0; j < 8; ++j) sh[stripe][s][j] = acc[j];
    __syncthreads();
    {
        int u = tid >> 3, j = tid & 7;   // 512 outputs
        float r = 0.f;
        #pragma unroll
        for (int st = 0; st < 8; ++st) r += sh[st][u][j];
        pooledp[((size_t)q * NSEG + b) * DIM + u * 8 + j] = r;
    }
}

// ---------------------------------------------------------------------------
// Kernel 4: sum 4 partials + LN(pn) -> outbf [256][512] bf16 row-major
// ---------------------------------------------------------------------------
__global__ __launch_bounds__(128) void k_pln(const float* __restrict__ pooledp,
                                             const float* __restrict__ pn_g,
                                             const float* __restrict__ pn_b,
                                             u16* __restrict__ outbf) {
    const int b = blockIdx.x, tid = threadIdx.x;   // 128 threads, 2 waves
    const f32x4* pp = reinterpret_cast<const f32x4*>(pooledp);
    f32x4 v = pp[(0 * NSEG + b) * 128 + tid] + pp[(1 * NSEG + b) * 128 + tid]
            + pp[(2 * NSEG + b) * 128 + tid] + pp[(3 * NSEG + b) * 128 + tid];
    float s = v[0] + v[1] + v[2] + v[3];
    float q = v[0]*v[0] + v[1]*v[1] + v[2]*v[2] + v[3]*v[3];
    #pragma unroll
    for (int off = 32; off; off >>= 1) {
        s += __shfl_xor(s, off);
        q += __shfl_xor(q, off);
    }
    __shared__ float sh[4];
    if ((tid & 63) == 0) { sh[(tid >> 6) * 2] = s; sh[(tid >> 6) * 2 + 1] = q; }
    __syncthreads();
    float S = sh[0] + sh[2], Q = sh[1] + sh[3];
    float mean = S * (1.0f / 512.0f);
    float rstd = rsqrtf(Q * (1.0f / 512.0f) - mean * mean + LNEPS);
    f32x4 g = reinterpret_cast<const f32x4*>(pn_g)[tid];
    f32x4 bb = reinterpret_cast<const f32x4*>(pn_b)[tid];
    bf16x4 o;
    #pragma unroll
    for (int j = 0; j < 4; ++j)
        o[j] = (bf16_t)((v[j] - mean) * rstd * g[j] + bb[j]);
    reinterpret_cast<bf16x4*>(outbf)[b * 128 + tid] = o;
}

// ---------------------------------------------------------------------------
// Kernel 5: y = outbf @ mW1.T + mb1   (MFMA).  grid (4 h-chunks, 2 seg-halves)
// ---------------------------------------------------------------------------
__global__ __launch_bounds__(512) void k_heady(const u16* __restrict__ outbf,
                                               const u16* __restrict__ mW1f,
                                               const float* __restrict__ mb1,
                                               float* __restrict__ y) {
    __shared__ __align__(16) u16 alds[128 * DIM];   // 128KB
    const int tid  = threadIdx.x;
    const int lane = tid & 63;
    const int w    = tid >> 6;
    const int wm   = w >> 2;            // 0..1
    const int wn   = w & 3;             // 0..3
    const int l15  = lane & 15;
    const int g4   = lane >> 4;
    const int hc   = blockIdx.x;        // 0..3
    const int sh_  = blockIdx.y;        // 0..1

    const uint4* srcU = reinterpret_cast<const uint4*>(outbf);
    #pragma unroll
    for (int uu = 0; uu < 16; ++uu) {
        int lu = uu * 512 + tid;        // 0..8191
        int r  = lu >> 6;               // 0..127
        int u  = lu & 63;
        uint4 val = srcU[(size_t)(sh_ * 128 + r) * 64 + u];
        int phys = r * DIM + ((u ^ (r & 7)) << 3);
        *reinterpret_cast<uint4*>(&alds[phys]) = val;
    }
    __syncthreads();

    f32x4 acc[4][4];
    #pragma unroll
    for (int m = 0; m < 4; ++m)
        #pragma unroll
        for (int t = 0; t < 4; ++t)
            acc[m][t] = (f32x4){0.f, 0.f, 0.f, 0.f};

    const bf16x8* __restrict__ WB = reinterpret_cast<const bf16x8*>(mW1f);
    #pragma unroll 4
    for (int ks = 0; ks < 16; ++ks) {
        bf16x8 b[4];
        #pragma unroll
        for (int t = 0; t < 4; ++t) {
            int nt_g = hc * 16 + wn * 4 + t;
            b[t] = WB[(ks * 64 + nt_g) * 64 + lane];
        }
        bf16x8 a[4];
        #pragma unroll
        for (int m = 0; m < 4; ++m) {
            int r = wm * 64 + m * 16 + l15;
            int u = ks * 4 + g4;
            a[m] = *reinterpret_cast<const bf16x8*>(&alds[r * DIM + ((u ^ (r & 7)) << 3)]);
        }
        #pragma unroll
        for (int m = 0; m < 4; ++m)
            #pragma unroll
            for (int t = 0; t < 4; ++t)
                acc[m][t] = __builtin_amdgcn_mfma_f32_16x16x32_bf16(a[m], b[t], acc[m][t], 0, 0, 0);
    }

    #pragma unroll
    for (int t = 0; t < 4; ++t) {
        int col = hc * 256 + (wn * 4 + t) * 16 + l15;
        float bias = mb1[col];
        #pragma unroll
        for (int m = 0; m < 4; ++m)
            #pragma unroll
            for (int j = 0; j < 4; ++j) {
                int seg = sh_ * 128 + wm * 64 + m * 16 + g4 * 4 + j;
                y[(size_t)seg * HDIM + col] = acc[m][t][j] + bias;
            }
    }
}

// ---------------------------------------------------------------------------
// Kernel 6: z = relu(LN(y)*mln_g+mln_b) -> zbf [256][1024] bf16
// ---------------------------------------------------------------------------
__global__ __launch_bounds__(256) void k_headz(const float* __restrict__ y,
                                               const float* __restrict__ mln_g,
                                               const float* __restrict__ mln_b,
                                               u16* __restrict__ zbf) {
    const int b = blockIdx.x, tid = threadIdx.x;   // 256 threads, 4 waves
    f32x4 v = reinterpret_cast<const f32x4*>(y)[b * 256 + tid];
    float s = v[0] + v[1] + v[2] + v[3];
    float q = v[0]*v[0] + v[1]*v[1] + v[2]*v[2] + v[3]*v[3];
    #pragma unroll
    for (int off = 32; off; off >>= 1) {
        s += __shfl_xor(s, off);
        q += __shfl_xor(q, off);
    }
    __shared__ float sh[8];
    if ((tid & 63) == 0) { sh[(tid >> 6) * 2] = s; sh[(tid >> 6) * 2 + 1] = q; }
    __syncthreads();
    float S = sh[0] + sh[2] + sh[4] + sh[6];
    float Q = sh[1] + sh[3] + sh[5] + sh[7];
    float mean = S * (1.0f / 1024.0f);
    float rstd = rsqrtf(Q * (1.0f / 1024.0f) - mean * mean + LNEPS);
    f32x4 g = reinterpret_cast<const f32x4*>(mln_g)[tid];
    f32x4 bb = reinterpret_cast<const f32x4*>(mln_b)[tid];
    bf16x4 o;
    #pragma unroll
    for (int j = 0; j < 4; ++j)
        o[j] = (bf16_t)fmaxf((v[j] - mean) * rstd * g[j] + bb[j], 0.f);
    reinterpret_cast<bf16x4*>(zbf)[b * 256 + tid] = o;
}

// ---------------------------------------------------------------------------
// Kernel 7: logits = zbf @ mW2.T + mb2  (MFMA). grid 2 (seg-halves).
// ---------------------------------------------------------------------------
__global__ __launch_bounds__(512) void k_logits(const u16* __restrict__ zbf,
                                                const u16* __restrict__ mW2f,
                                                const float* __restrict__ mb2,
                                                float* __restrict__ logits) {
    __shared__ __align__(16) u16 alds[128 * 256];   // 64KB
    const int tid  = threadIdx.x;
    const int lane = tid & 63;
    const int w    = tid >> 6;
    const int wm   = w >> 2;
    const int wn   = w & 3;
    const int l15  = lane & 15;
    const int g4   = lane >> 4;
    const int sh_  = blockIdx.x;        // 0..1

    f32x4 acc[4][4];
    #pragma unroll
    for (int m = 0; m < 4; ++m)
        #pragma unroll
        for (int t = 0; t < 4; ++t)
            acc[m][t] = (f32x4){0.f, 0.f, 0.f, 0.f};

    const uint4* srcU = reinterpret_cast<const uint4*>(zbf);
    const bf16x8* __restrict__ WB = reinterpret_cast<const bf16x8*>(mW2f);

    for (int kc = 0; kc < 4; ++kc) {
        __syncthreads();
        #pragma unroll
        for (int uu = 0; uu < 8; ++uu) {
            int lu = uu * 512 + tid;    // 0..4095
            int r  = lu >> 5;           // 0..127
            int u  = lu & 31;
            uint4 val = srcU[(size_t)(sh_ * 128 + r) * 128 + kc * 32 + u];
            int phys = r * 256 + ((u ^ (r & 7)) << 3);
            *reinterpret_cast<uint4*>(&alds[phys]) = val;
        }
        __syncthreads();
        #pragma unroll
        for (int ksl = 0; ksl < 8; ++ksl) {
            bf16x8 b[4];
            #pragma unroll
            for (int t = 0; t < 4; ++t)
                b[t] = WB[((kc * 8 + ksl) * 16 + wn * 4 + t) * 64 + lane];
            bf16x8 a[4];
            #pragma unroll
            for (int m = 0; m < 4; ++m) {
                int r = wm * 64 + m * 16 + l15;
                int u = ksl * 4 + g4;
                a[m] = *reinterpret_cast<const bf16x8*>(&alds[r * 256 + ((u ^ (r & 7)) << 3)]);
            }
            #pragma unroll
            for (int m = 0; m < 4; ++m)
                #pragma unroll
                for (int t = 0; t < 4; ++t)
                    acc[m][t] = __builtin_amdgcn_mfma_f32_16x16x32_bf16(a[m], b[t], acc[m][t], 0, 0, 0);
        }
    }

    #pragma unroll
    for (int t = 0; t < 4; ++t) {
        int col = (wn * 4 + t) * 16 + l15;   // 0..255
        if (col < OUTF) {
            float bias = mb2[col];
            #pragma unroll
            for (int m = 0; m < 4; ++m)
                #pragma unroll
                for (int j = 0; j < 4; ++j) {
                    int seg = sh_ * 128 + wm * 64 + m * 16 + g4 * 4 + j;
                    logits[(size_t)seg * OUTF + col] = acc[m][t][j] + bias;
                }
        }
    }
}

// ---------------------------------------------------------------------------
extern "C" void kernel_launch(void* const* d_in, const int* in_sizes, int n_in,
                              void* d_out, int out_size, void* d_ws, size_t ws_size,
                              hipStream_t stream) {
    const float* x     = (const float*)d_in[0];
    const int*   ids   = (const int*)  d_in[1];
    const float* gW1   = (const float*)d_in[2];
    const float* gb1   = (const float*)d_in[3];
    const float* gln_g = (const float*)d_in[4];
    const float* gln_b = (const float*)d_in[5];
    const float* gW2   = (const float*)d_in[6];
    const float* gb2   = (const float*)d_in[7];
    const float* pn_g  = (const float*)d_in[8];
    const float* pn_b  = (const float*)d_in[9];
    const float* mW1   = (const float*)d_in[10];
    const float* mb1   = (const float*)d_in[11];
    const float* mln_g = (const float*)d_in[12];
    const float* mln_b = (const float*)d_in[13];
    const float* mW2   = (const float*)d_in[14];
    const float* mb2   = (const float*)d_in[15];
    float* logits = (float*)d_out;

    char* ws = (char*)d_ws;
    const size_t MB = 1 << 20;
    u16*   Wf      = (u16*)  (ws);                  // 1 MB
    u16*   mW1f    = (u16*)  (ws + 1 * MB);         // 1 MB
    u16*   mW2f    = (u16*)  (ws + 2 * MB);         // 512 KB
    float* gate    = (float*)(ws + 5 * MB / 2);     // 400 KB
    float* segmax  = (float*)(ws + 3 * MB);         // 1 KB
    float* segden  = segmax + NSEG;
    float* pooledp = (float*)(ws + 4 * MB);         // 2 MB
    u16*   outbf   = (u16*)  (ws + 6 * MB);         // 256 KB
    float* y       = (float*)(ws + 7 * MB);         // 1 MB
    u16*   zbf     = (u16*)  (ws + 8 * MB);         // 512 KB
    u16*   xbf     = (u16*)  (ws + 16 * MB);        // 100032*512*2 = ~98 MB

    hipLaunchKernelGGL(k_conv, dim3(640 + 25008), dim3(256), 0, stream,
                       gW1, mW1, mW2, x, Wf, mW1f, mW2f, xbf);
    hipLaunchKernelGGL(k_gate, dim3(GATE_GRID), dim3(1024), 0, stream,
                       xbf, Wf, gb1, gln_g, gln_b, gW2, gb2, gate);
    hipLaunchKernelGGL(k_seg, dim3(NSEG), dim3(256), 0, stream,
                       ids, gate, segmax, segden);
    hipLaunchKernelGGL(k_poolp, dim3(NSEG, 4), dim3(512), 0, stream,
                       ids, gate, xbf, segmax, segden, pooledp);
    hipLaunchKernelGGL(k_pln, dim3(NSEG), dim3(128), 0, stream,
                       pooledp, pn_g, pn_b, outbf);
    hipLaunchKernelGGL(k_heady, dim3(4, 2), dim3(512), 0, stream,
                       outbf, mW1f, mb1, y);
    hipLaunchKernelGGL(k_headz, dim3(NSEG), dim3(256), 0, stream,
                       y, mln_g, mln_b, zbf);
    hipLaunchKernelGGL(k_logits, dim3(2), dim3(512), 0, stream,
                       zbf, mW2f, mb2, logits);
}

// Round 8
// 241.959 us; speedup vs baseline: 2.7795x; 2.7795x over previous
//
#include <hip/hip_runtime.h>
#include <stdint.h>

typedef unsigned int u32;
typedef unsigned short u16;

#define NROWS 100000
#define DIM 512
#define HDIM 1024
#define OUTF 250
#define NSEG 256
#define LNEPS 1e-5f
#define BM 32
#define NG 3125            // 100000/32
#define PQ 8               // pool partial splits

typedef __bf16 bf16_t;
typedef bf16_t bf16x4 __attribute__((ext_vector_type(4)));
typedef bf16_t bf16x8 __attribute__((ext_vector_type(8)));
typedef float f32x4 __attribute__((ext_vector_type(4)));

__device__ inline int lower_bound(const int* __restrict__ a, int n, int v) {
    int lo = 0, hi = n;
    while (lo < hi) {
        int m = (lo + hi) >> 1;
        if (a[m] < v) lo = m + 1; else hi = m;
    }
    return lo;
}

// ---------------------------------------------------------------------------
// Kernel 0: convert gW1, mW1 ([1024][512]) and mW2 ([250->256 pad][1024])
// fp32 -> bf16 MFMA B-fragment order.
// Frag layout [ks][nt][lane] x 16B: n = nt*16+(lane&15), k = ks*32+(lane>>4)*8+j
// ---------------------------------------------------------------------------
__global__ __launch_bounds__(256) void k_conv(const float* __restrict__ gW1,
                                              const float* __restrict__ mW1,
                                              const float* __restrict__ mW2,
                                              u16* __restrict__ Wf,
                                              u16* __restrict__ mW1f,
                                              u16* __restrict__ mW2f) {
    int bid = blockIdx.x;
    if (bid < 512) {
        const float* src_base = (bid < 256) ? gW1 : mW1;
        u16* dst = (bid < 256) ? Wf : mW1f;
        int gid  = (bid & 255) * 256 + threadIdx.x;   // 0..65535
        int lane = gid & 63;
        int grp  = gid >> 6;                          // ks*64 + nt
        int ks   = grp >> 6, nt = grp & 63;
        int n    = nt * 16 + (lane & 15);
        int k0   = ks * 32 + ((lane >> 4) << 3);
        const float* src = src_base + (size_t)n * DIM + k0;
        float4 f0 = *reinterpret_cast<const float4*>(src);
        float4 f1 = *reinterpret_cast<const float4*>(src + 4);
        bf16x8 v;
        v[0] = (bf16_t)f0.x; v[1] = (bf16_t)f0.y;
        v[2] = (bf16_t)f0.z; v[3] = (bf16_t)f0.w;
        v[4] = (bf16_t)f1.x; v[5] = (bf16_t)f1.y;
        v[6] = (bf16_t)f1.z; v[7] = (bf16_t)f1.w;
        reinterpret_cast<bf16x8*>(dst)[gid] = v;
    } else {
        int gid  = (bid - 512) * 256 + threadIdx.x;   // 0..32767
        int lane = gid & 63;
        int grp  = gid >> 6;                          // ks*16 + nt
        int ks   = grp >> 4, nt = grp & 15;
        int n    = nt * 16 + (lane & 15);             // 0..255
        int k0   = ks * 32 + ((lane >> 4) << 3);
        bf16x8 v;
        if (n < OUTF) {
            const float* src = mW2 + (size_t)n * HDIM + k0;
            float4 f0 = *reinterpret_cast<const float4*>(src);
            float4 f1 = *reinterpret_cast<const float4*>(src + 4);
            v[0] = (bf16_t)f0.x; v[1] = (bf16_t)f0.y;
            v[2] = (bf16_t)f0.z; v[3] = (bf16_t)f0.w;
            v[4] = (bf16_t)f1.x; v[5] = (bf16_t)f1.y;
            v[6] = (bf16_t)f1.z; v[7] = (bf16_t)f1.w;
        } else {
            #pragma unroll
            for (int j = 0; j < 8; ++j) v[j] = (bf16_t)0.f;
        }
        reinterpret_cast<bf16x8*>(mW2f)[gid] = v;
    }
}

// ---------------------------------------------------------------------------
// Kernel 1: fused  gate[i] = relu(LN(x_i @ gW1.T + gb1)) . gW2 + gb2
// Round-4 proven structure: BM=32 (grid 3125), 8 waves, wave w owns cols
// [128w,128w+128); reg-staged LDS, pipelined K-loop (b/a double-buffered in
// regs, compiler collapses live set to VGPR 60 + 64 AGPR, no spill).
// ---------------------------------------------------------------------------
__global__ __launch_bounds__(512) void k_gate(
    const float* __restrict__ x, const u16* __restrict__ Wf,
    const float* __restrict__ gb1,
    const float* __restrict__ gln_g, const float* __restrict__ gln_b,
    const float* __restrict__ gW2, const float* __restrict__ gb2,
    float* __restrict__ gate)
{
    __shared__ __align__(16) u16 xlds[BM * DIM];   // 32KB, XOR-swizzled 16B units
    __shared__ float redS[8][BM];
    __shared__ float redQ[8][BM];
    __shared__ float meanA[BM], rstdA[BM];

    const int tid  = threadIdx.x;
    const int lane = tid & 63;
    const int w    = tid >> 6;          // wave 0..7
    const int l15  = lane & 15;
    const int g4   = lane >> 4;         // 0..3
    const int row0 = blockIdx.x * BM;

    // ---- stage x rows -> LDS bf16 (swizzled: unit u of row r at (u ^ (r&7)))
    #pragma unroll
    for (int uu = 0; uu < 4; ++uu) {
        int lu  = uu * 512 + tid;       // unit id 0..2047 (unit = 8 elements)
        int r   = lu >> 6;
        int u   = lu & 63;
        const float* src = x + (size_t)(row0 + r) * DIM + (u << 3);
        float4 f0 = *reinterpret_cast<const float4*>(src);
        float4 f1 = *reinterpret_cast<const float4*>(src + 4);
        bf16x8 v;
        v[0] = (bf16_t)f0.x; v[1] = (bf16_t)f0.y;
        v[2] = (bf16_t)f0.z; v[3] = (bf16_t)f0.w;
        v[4] = (bf16_t)f1.x; v[5] = (bf16_t)f1.y;
        v[6] = (bf16_t)f1.z; v[7] = (bf16_t)f1.w;
        int phys = r * DIM + ((u ^ (r & 7)) << 3);   // u16 units
        *reinterpret_cast<bf16x8*>(&xlds[phys]) = v;
    }
    __syncthreads();

    // ---- pipelined K loop
    f32x4 acc[2][8];
    #pragma unroll
    for (int m = 0; m < 2; ++m)
        #pragma unroll
        for (int t = 0; t < 8; ++t)
            acc[m][t] = (f32x4){0.f, 0.f, 0.f, 0.f};

    const bf16x8* __restrict__ WfB = reinterpret_cast<const bf16x8*>(Wf);

    auto loadB = [&](bf16x8 (&b)[8], int ks) {
        #pragma unroll
        for (int t = 0; t < 8; ++t)
            b[t] = WfB[(ks * 64 + w * 8 + t) * 64 + lane];
    };
    auto loadA = [&](bf16x8 (&a)[2], int ks) {
        #pragma unroll
        for (int m = 0; m < 2; ++m) {
            int r = m * 16 + l15;
            int u = ks * 4 + g4;
            a[m] = *reinterpret_cast<const bf16x8*>(&xlds[r * DIM + ((u ^ (r & 7)) << 3)]);
        }
    };
    auto domfma = [&](bf16x8 (&a)[2], bf16x8 (&b)[8]) {
        #pragma unroll
        for (int m = 0; m < 2; ++m)
            #pragma unroll
            for (int t = 0; t < 8; ++t)
                acc[m][t] = __builtin_amdgcn_mfma_f32_16x16x32_bf16(a[m], b[t], acc[m][t], 0, 0, 0);
    };

    bf16x8 b0[8], b1[8], a0[2], a1[2];
    loadB(b0, 0); loadA(a0, 0);
    #pragma unroll
    for (int ks2 = 0; ks2 < 8; ++ks2) {
        loadB(b1, 2 * ks2 + 1);
        loadA(a1, 2 * ks2 + 1);
        domfma(a0, b0);
        if (ks2 < 7) {
            loadB(b0, 2 * ks2 + 2);
            loadA(a0, 2 * ks2 + 2);
        }
        domfma(a1, b1);
    }

    // ---- bias add (affects LN stats)
    float cbias[8];
    #pragma unroll
    for (int t = 0; t < 8; ++t) cbias[t] = gb1[(w * 8 + t) * 16 + l15];
    #pragma unroll
    for (int m = 0; m < 2; ++m)
        #pragma unroll
        for (int t = 0; t < 8; ++t)
            #pragma unroll
            for (int j = 0; j < 4; ++j)
                acc[m][t][j] += cbias[t];

    // ---- per-row LN stats, streamed per row-slot
    #pragma unroll
    for (int m = 0; m < 2; ++m) {
        #pragma unroll
        for (int j = 0; j < 4; ++j) {
            float s1 = 0.f, s2 = 0.f;
            #pragma unroll
            for (int t = 0; t < 8; ++t) {
                float v = acc[m][t][j];
                s1 += v; s2 += v * v;
            }
            #pragma unroll
            for (int off = 1; off < 16; off <<= 1) {
                s1 += __shfl_xor(s1, off);
                s2 += __shfl_xor(s2, off);
            }
            if (l15 == 0) {
                int row = m * 16 + g4 * 4 + j;
                redS[w][row] = s1;
                redQ[w][row] = s2;
            }
        }
    }
    __syncthreads();
    if (tid < BM) {
        float S1 = 0.f, S2 = 0.f;
        #pragma unroll
        for (int ww = 0; ww < 8; ++ww) { S1 += redS[ww][tid]; S2 += redQ[ww][tid]; }
        float mean = S1 * (1.0f / 1024.0f);
        float var  = S2 * (1.0f / 1024.0f) - mean * mean;
        meanA[tid] = mean;
        rstdA[tid] = rsqrtf(var + LNEPS);
    }
    __syncthreads();

    // ---- LN + relu + dot(gW2), streamed per row-slot
    float cg[8], cb[8], cw[8];
    #pragma unroll
    for (int t = 0; t < 8; ++t) {
        int c = (w * 8 + t) * 16 + l15;
        cg[t] = gln_g[c]; cb[t] = gln_b[c]; cw[t] = gW2[c];
    }
    #pragma unroll
    for (int m = 0; m < 2; ++m) {
        #pragma unroll
        for (int j = 0; j < 4; ++j) {
            int row = m * 16 + g4 * 4 + j;
            float mn = meanA[row];
            float rs = rstdA[row];
            float gp = 0.f;
            #pragma unroll
            for (int t = 0; t < 8; ++t) {
                float h = (acc[m][t][j] - mn) * rs * cg[t] + cb[t];
                gp += fmaxf(h, 0.f) * cw[t];
            }
            #pragma unroll
            for (int off = 1; off < 16; off <<= 1)
                gp += __shfl_xor(gp, off);
            if (l15 == 0) redS[w][row] = gp;
        }
    }
    __syncthreads();
    if (tid < BM) {
        float s = gb2[0];
        #pragma unroll
        for (int ww = 0; ww < 8; ++ww) s += redS[ww][tid];
        gate[row0 + tid] = s;
    }
}

// ---------------------------------------------------------------------------
// Kernel 2: fused segment softmax + partial pooled sums.
// grid (NSEG, PQ) x 512 thr. Each block computes its segment's max/denom
// inline (gate is L2-resident), then partial weighted x-sums for its
// (q, stripe) row classes. pooledp[q][b][512].
// ---------------------------------------------------------------------------
__global__ __launch_bounds__(512) void k_poolseg(const int* __restrict__ ids,
                                                 const float* __restrict__ gate,
                                                 const float* __restrict__ x,
                                                 float* __restrict__ pooledp) {
    const int b = blockIdx.x, q = blockIdx.y, tid = threadIdx.x;
    const int start = lower_bound(ids, NROWS, b);
    const int end   = lower_bound(ids, NROWS, b + 1);

    __shared__ float red8[8];

    // ---- segment max
    float lm = -INFINITY;
    for (int i = start + tid; i < end; i += 512) lm = fmaxf(lm, gate[i]);
    #pragma unroll
    for (int off = 32; off; off >>= 1) lm = fmaxf(lm, __shfl_xor(lm, off));
    if ((tid & 63) == 0) red8[tid >> 6] = lm;
    __syncthreads();
    float m = red8[0];
    #pragma unroll
    for (int ww = 1; ww < 8; ++ww) m = fmaxf(m, red8[ww]);
    __syncthreads();

    // ---- segment sum(exp)
    float ls = 0.f;
    for (int i = start + tid; i < end; i += 512) ls += __expf(gate[i] - m);
    #pragma unroll
    for (int off = 32; off; off >>= 1) ls += __shfl_xor(ls, off);
    if ((tid & 63) == 0) red8[tid >> 6] = ls;
    __syncthreads();
    float den = 0.f;
    #pragma unroll
    for (int ww = 0; ww < 8; ++ww) den += red8[ww];
    const float inv = (den > 0.f) ? 1.0f / den : 0.0f;
    __syncthreads();

    // ---- partial pool: rows i = start + q*4 + stripe, step 32
    const int slot   = tid & 127;     // f4 column slot
    const int stripe = tid >> 7;      // 0..3
    __shared__ f32x4 sh[4][128];      // 8 KB

    const f32x4* __restrict__ xr = reinterpret_cast<const f32x4*>(x);
    f32x4 acc = (f32x4){0.f, 0.f, 0.f, 0.f};
    for (int i = start + q * 4 + stripe; i < end; i += 4 * PQ) {
        float wgt = __expf(gate[i] - m) * inv;
        f32x4 xv = xr[(size_t)i * 128 + slot];
        acc += wgt * xv;
    }
    sh[stripe][slot] = acc;
    __syncthreads();
    if (tid < 128) {
        f32x4 r = sh[0][tid] + sh[1][tid] + sh[2][tid] + sh[3][tid];
        reinterpret_cast<f32x4*>(pooledp)[((size_t)q * NSEG + b) * 128 + tid] = r;
    }
}

// ---------------------------------------------------------------------------
// Kernel 3: sum PQ partials + LN(pn) -> outbf [256][512] bf16 row-major
// ---------------------------------------------------------------------------
__global__ __launch_bounds__(128) void k_pln(const float* __restrict__ pooledp,
                                             const float* __restrict__ pn_g,
                                             const float* __restrict__ pn_b,
                                             u16* __restrict__ outbf) {
    const int b = blockIdx.x, tid = threadIdx.x;   // 128 threads, 2 waves
    const f32x4* pp = reinterpret_cast<const f32x4*>(pooledp);
    f32x4 v = (f32x4){0.f, 0.f, 0.f, 0.f};
    #pragma unroll
    for (int qq = 0; qq < PQ; ++qq)
        v += pp[((size_t)qq * NSEG + b) * 128 + tid];
    float s = v[0] + v[1] + v[2] + v[3];
    float q = v[0]*v[0] + v[1]*v[1] + v[2]*v[2] + v[3]*v[3];
    #pragma unroll
    for (int off = 32; off; off >>= 1) {
        s += __shfl_xor(s, off);
        q += __shfl_xor(q, off);
    }
    __shared__ float sh[4];
    if ((tid & 63) == 0) { sh[(tid >> 6) * 2] = s; sh[(tid >> 6) * 2 + 1] = q; }
    __syncthreads();
    float S = sh[0] + sh[2], Q = sh[1] + sh[3];
    float mean = S * (1.0f / 512.0f);
    float rstd = rsqrtf(Q * (1.0f / 512.0f) - mean * mean + LNEPS);
    f32x4 g = reinterpret_cast<const f32x4*>(pn_g)[tid];
    f32x4 bb = reinterpret_cast<const f32x4*>(pn_b)[tid];
    bf16x4 o;
    #pragma unroll
    for (int j = 0; j < 4; ++j)
        o[j] = (bf16_t)((v[j] - mean) * rstd * g[j] + bb[j]);
    reinterpret_cast<bf16x4*>(outbf)[b * 128 + tid] = o;
}

// ---------------------------------------------------------------------------
// Kernel 4: y = outbf @ mW1.T + mb1   (MFMA).  grid (4 h-chunks, 2 seg-halves)
// ---------------------------------------------------------------------------
__global__ __launch_bounds__(512) void k_heady(const u16* __restrict__ outbf,
                                               const u16* __restrict__ mW1f,
                                               const float* __restrict__ mb1,
                                               float* __restrict__ y) {
    __shared__ __align__(16) u16 alds[128 * DIM];   // 128KB
    const int tid  = threadIdx.x;
    const int lane = tid & 63;
    const int w    = tid >> 6;
    const int wm   = w >> 2;            // 0..1
    const int wn   = w & 3;             // 0..3
    const int l15  = lane & 15;
    const int g4   = lane >> 4;
    const int hc   = blockIdx.x;        // 0..3
    const int sh_  = blockIdx.y;        // 0..1

    const uint4* srcU = reinterpret_cast<const uint4*>(outbf);
    #pragma unroll
    for (int uu = 0; uu < 16; ++uu) {
        int lu = uu * 512 + tid;        // 0..8191
        int r  = lu >> 6;               // 0..127
        int u  = lu & 63;
        uint4 val = srcU[(size_t)(sh_ * 128 + r) * 64 + u];
        int phys = r * DIM + ((u ^ (r & 7)) << 3);
        *reinterpret_cast<uint4*>(&alds[phys]) = val;
    }
    __syncthreads();

    f32x4 acc[4][4];
    #pragma unroll
    for (int m = 0; m < 4; ++m)
        #pragma unroll
        for (int t = 0; t < 4; ++t)
            acc[m][t] = (f32x4){0.f, 0.f, 0.f, 0.f};

    const bf16x8* __restrict__ WB = reinterpret_cast<const bf16x8*>(mW1f);
    #pragma unroll 4
    for (int ks = 0; ks < 16; ++ks) {
        bf16x8 b[4];
        #pragma unroll
        for (int t = 0; t < 4; ++t) {
            int nt_g = hc * 16 + wn * 4 + t;
            b[t] = WB[(ks * 64 + nt_g) * 64 + lane];
        }
        bf16x8 a[4];
        #pragma unroll
        for (int m = 0; m < 4; ++m) {
            int r = wm * 64 + m * 16 + l15;
            int u = ks * 4 + g4;
            a[m] = *reinterpret_cast<const bf16x8*>(&alds[r * DIM + ((u ^ (r & 7)) << 3)]);
        }
        #pragma unroll
        for (int m = 0; m < 4; ++m)
            #pragma unroll
            for (int t = 0; t < 4; ++t)
                acc[m][t] = __builtin_amdgcn_mfma_f32_16x16x32_bf16(a[m], b[t], acc[m][t], 0, 0, 0);
    }

    #pragma unroll
    for (int t = 0; t < 4; ++t) {
        int col = hc * 256 + (wn * 4 + t) * 16 + l15;
        float bias = mb1[col];
        #pragma unroll
        for (int m = 0; m < 4; ++m)
            #pragma unroll
            for (int j = 0; j < 4; ++j) {
                int seg = sh_ * 128 + wm * 64 + m * 16 + g4 * 4 + j;
                y[(size_t)seg * HDIM + col] = acc[m][t][j] + bias;
            }
    }
}

// ---------------------------------------------------------------------------
// Kernel 5: z = relu(LN(y)*mln_g+mln_b) -> zbf [256][1024] bf16
// ---------------------------------------------------------------------------
__global__ __launch_bounds__(256) void k_headz(const float* __restrict__ y,
                                               const float* __restrict__ mln_g,
                                               const float* __restrict__ mln_b,
                                               u16* __restrict__ zbf) {
    const int b = blockIdx.x, tid = threadIdx.x;   // 256 threads, 4 waves
    f32x4 v = reinterpret_cast<const f32x4*>(y)[b * 256 + tid];
    float s = v[0] + v[1] + v[2] + v[3];
    float q = v[0]*v[0] + v[1]*v[1] + v[2]*v[2] + v[3]*v[3];
    #pragma unroll
    for (int off = 32; off; off >>= 1) {
        s += __shfl_xor(s, off);
        q += __shfl_xor(q, off);
    }
    __shared__ float sh[8];
    if ((tid & 63) == 0) { sh[(tid >> 6) * 2] = s; sh[(tid >> 6) * 2 + 1] = q; }
    __syncthreads();
    float S = sh[0] + sh[2] + sh[4] + sh[6];
    float Q = sh[1] + sh[3] + sh[5] + sh[7];
    float mean = S * (1.0f / 1024.0f);
    float rstd = rsqrtf(Q * (1.0f / 1024.0f) - mean * mean + LNEPS);
    f32x4 g = reinterpret_cast<const f32x4*>(mln_g)[tid];
    f32x4 bb = reinterpret_cast<const f32x4*>(mln_b)[tid];
    bf16x4 o;
    #pragma unroll
    for (int j = 0; j < 4; ++j)
        o[j] = (bf16_t)fmaxf((v[j] - mean) * rstd * g[j] + bb[j], 0.f);
    reinterpret_cast<bf16x4*>(zbf)[b * 256 + tid] = o;
}

// ---------------------------------------------------------------------------
// Kernel 6: logits = zbf @ mW2.T + mb2  (MFMA). grid 2 (seg-halves).
// ---------------------------------------------------------------------------
__global__ __launch_bounds__(512) void k_logits(const u16* __restrict__ zbf,
                                                const u16* __restrict__ mW2f,
                                                const float* __restrict__ mb2,
                                                float* __restrict__ logits) {
    __shared__ __align__(16) u16 alds[128 * 256];   // 64KB
    const int tid  = threadIdx.x;
    const int lane = tid & 63;
    const int w    = tid >> 6;
    const int wm   = w >> 2;
    const int wn   = w & 3;
    const int l15  = lane & 15;
    const int g4   = lane >> 4;
    const int sh_  = blockIdx.x;        // 0..1

    f32x4 acc[4][4];
    #pragma unroll
    for (int m = 0; m < 4; ++m)
        #pragma unroll
        for (int t = 0; t < 4; ++t)
            acc[m][t] = (f32x4){0.f, 0.f, 0.f, 0.f};

    const uint4* srcU = reinterpret_cast<const uint4*>(zbf);
    const bf16x8* __restrict__ WB = reinterpret_cast<const bf16x8*>(mW2f);

    for (int kc = 0; kc < 4; ++kc) {
        __syncthreads();
        #pragma unroll
        for (int uu = 0; uu < 8; ++uu) {
            int lu = uu * 512 + tid;    // 0..4095
            int r  = lu >> 5;           // 0..127
            int u  = lu & 31;
            uint4 val = srcU[(size_t)(sh_ * 128 + r) * 128 + kc * 32 + u];
            int phys = r * 256 + ((u ^ (r & 7)) << 3);
            *reinterpret_cast<uint4*>(&alds[phys]) = val;
        }
        __syncthreads();
        #pragma unroll
        for (int ksl = 0; ksl < 8; ++ksl) {
            bf16x8 b[4];
            #pragma unroll
            for (int t = 0; t < 4; ++t)
                b[t] = WB[((kc * 8 + ksl) * 16 + wn * 4 + t) * 64 + lane];
            bf16x8 a[4];
            #pragma unroll
            for (int m = 0; m < 4; ++m) {
                int r = wm * 64 + m * 16 + l15;
                int u = ksl * 4 + g4;
                a[m] = *reinterpret_cast<const bf16x8*>(&alds[r * 256 + ((u ^ (r & 7)) << 3)]);
            }
            #pragma unroll
            for (int m = 0; m < 4; ++m)
                #pragma unroll
                for (int t = 0; t < 4; ++t)
                    acc[m][t] = __builtin_amdgcn_mfma_f32_16x16x32_bf16(a[m], b[t], acc[m][t], 0, 0, 0);
        }
    }

    #pragma unroll
    for (int t = 0; t < 4; ++t) {
        int col = (wn * 4 + t) * 16 + l15;   // 0..255
        if (col < OUTF) {
            float bias = mb2[col];
            #pragma unroll
            for (int m = 0; m < 4; ++m)
                #pragma unroll
                for (int j = 0; j < 4; ++j) {
                    int seg = sh_ * 128 + wm * 64 + m * 16 + g4 * 4 + j;
                    logits[(size_t)seg * OUTF + col] = acc[m][t][j] + bias;
                }
        }
    }
}

// ---------------------------------------------------------------------------
extern "C" void kernel_launch(void* const* d_in, const int* in_sizes, int n_in,
                              void* d_out, int out_size, void* d_ws, size_t ws_size,
                              hipStream_t stream) {
    const float* x     = (const float*)d_in[0];
    const int*   ids   = (const int*)  d_in[1];
    const float* gW1   = (const float*)d_in[2];
    const float* gb1   = (const float*)d_in[3];
    const float* gln_g = (const float*)d_in[4];
    const float* gln_b = (const float*)d_in[5];
    const float* gW2   = (const float*)d_in[6];
    const float* gb2   = (const float*)d_in[7];
    const float* pn_g  = (const float*)d_in[8];
    const float* pn_b  = (const float*)d_in[9];
    const float* mW1   = (const float*)d_in[10];
    const float* mb1   = (const float*)d_in[11];
    const float* mln_g = (const float*)d_in[12];
    const float* mln_b = (const float*)d_in[13];
    const float* mW2   = (const float*)d_in[14];
    const float* mb2   = (const float*)d_in[15];
    float* logits = (float*)d_out;

    char* ws = (char*)d_ws;
    const size_t MB = 1 << 20;
    u16*   Wf      = (u16*)  (ws);                  // 1 MB
    u16*   mW1f    = (u16*)  (ws + 1 * MB);         // 1 MB
    u16*   mW2f    = (u16*)  (ws + 2 * MB);         // 512 KB
    float* gate    = (float*)(ws + 5 * MB / 2);     // 400 KB
    float* pooledp = (float*)(ws + 4 * MB);         // PQ*256*512*4 = 4 MB
    u16*   outbf   = (u16*)  (ws + 8 * MB);         // 256 KB
    float* y       = (float*)(ws + 9 * MB);         // 1 MB
    u16*   zbf     = (u16*)  (ws + 10 * MB);        // 512 KB

    hipLaunchKernelGGL(k_conv, dim3(640), dim3(256), 0, stream,
                       gW1, mW1, mW2, Wf, mW1f, mW2f);
    hipLaunchKernelGGL(k_gate, dim3(NG), dim3(512), 0, stream,
                       x, Wf, gb1, gln_g, gln_b, gW2, gb2, gate);
    hipLaunchKernelGGL(k_poolseg, dim3(NSEG, PQ), dim3(512), 0, stream,
                       ids, gate, x, pooledp);
    hipLaunchKernelGGL(k_pln, dim3(NSEG), dim3(128), 0, stream,
                       pooledp, pn_g, pn_b, outbf);
    hipLaunchKernelGGL(k_heady, dim3(4, 2), dim3(512), 0, stream,
                       outbf, mW1f, mb1, y);
    hipLaunchKernelGGL(k_headz, dim3(NSEG), dim3(256), 0, stream,
                       y, mln_g, mln_b, zbf);
    hipLaunchKernelGGL(k_logits, dim3(2), dim3(512), 0, stream,
                       zbf, mW2f, mb2, logits);
}